// Round 2
// baseline (229.133 us; speedup 1.0000x reference)
//
#include <hip/hip_runtime.h>
#include <cstdint>
#include <cstddef>

#define LN_EPS 1e-5f

typedef float  f32x4  __attribute__((ext_vector_type(4)));
typedef __bf16 bf16x8 __attribute__((ext_vector_type(8)));
typedef __bf16 bf16x4 __attribute__((ext_vector_type(4)));

// ---------------------------------------------------------------- block reduce
__device__ __forceinline__ float block_sum(float v, volatile float* red) {
#pragma unroll
  for (int o = 32; o > 0; o >>= 1) v += __shfl_down(v, o, 64);
  const int lane = threadIdx.x & 63, w = threadIdx.x >> 6;
  __syncthreads();                 // protect red reuse across calls
  if (lane == 0) red[w] = v;
  __syncthreads();
  return red[0] + red[1] + red[2] + red[3];
}

// ---------------------------------------------------------------- LayerNorm
__global__ __launch_bounds__(256)
void k_ln(const float* __restrict__ seq, const float* __restrict__ g,
          const float* __restrict__ b, float* __restrict__ xn) {
  __shared__ float red[8];
  const int row = blockIdx.x, t = threadIdx.x;
  const f32x4 x = ((const f32x4*)(seq + (size_t)row * 1024))[t];
  float s  = x[0] + x[1] + x[2] + x[3];
  float s2 = x[0]*x[0] + x[1]*x[1] + x[2]*x[2] + x[3]*x[3];
#pragma unroll
  for (int o = 32; o > 0; o >>= 1) { s += __shfl_down(s, o, 64); s2 += __shfl_down(s2, o, 64); }
  const int lane = t & 63, w = t >> 6;
  if (lane == 0) { red[w] = s; red[4 + w] = s2; }
  __syncthreads();
  s  = red[0] + red[1] + red[2] + red[3];
  s2 = red[4] + red[5] + red[6] + red[7];
  const float mu  = s * (1.f / 1024.f);
  const float inv = rsqrtf(s2 * (1.f / 1024.f) - mu * mu + LN_EPS);
  const f32x4 gg = ((const f32x4*)g)[t];
  const f32x4 bb = ((const f32x4*)b)[t];
  f32x4 y;
#pragma unroll
  for (int i = 0; i < 4; ++i) y[i] = (x[i] - mu) * inv * gg[i] + bb[i];
  ((f32x4*)(xn + (size_t)row * 1024))[t] = y;
}

// ---------------------------------------------------------------- causal conv + silu
__global__ __launch_bounds__(256)
void k_conv(const float* __restrict__ xt, const float* __restrict__ cw,
            const float* __restrict__ cb, float* __restrict__ xc) {
  __shared__ float s[2048];
  const int row = blockIdx.x, t = threadIdx.x;
  const f32x4* src = (const f32x4*)(xt + (size_t)row * 2048);
  ((f32x4*)s)[t] = src[t];
  ((f32x4*)s)[t + 256] = src[t + 256];
  const float w0 = cw[0], w1 = cw[1], w2 = cw[2], w3 = cw[3], b = cb[0];
  __syncthreads();
  float out[8];
  const int c0 = t * 8;
#pragma unroll
  for (int j = 0; j < 8; ++j) {
    const int c = c0 + j;
    float a = b + w3 * s[c];
    if (c >= 1) a += w2 * s[c - 1];
    if (c >= 2) a += w1 * s[c - 2];
    if (c >= 3) a += w0 * s[c - 3];
    a = a / (1.f + __expf(-a));        // silu
    out[j] = a;
  }
  f32x4* dst = (f32x4*)(xc + (size_t)row * 2048 + c0);
  f32x4 v0 = {out[0], out[1], out[2], out[3]};
  f32x4 v1 = {out[4], out[5], out[6], out[7]};
  dst[0] = v0; dst[1] = v1;
}

// ---------------------------------------------------------------- i/f gates
__global__ __launch_bounds__(256)
void k_if(const float* __restrict__ xc, const float* __restrict__ Wi,
          const float* __restrict__ bi, const float* __restrict__ Wf,
          const float* __restrict__ bfp, const float* __restrict__ m_tm1,
          float* __restrict__ m_out, float* __restrict__ ig, float* __restrict__ fg) {
  __shared__ float sx[2048];
  __shared__ float so[16];
  __shared__ float red[4];
  const int row = blockIdx.x, t = threadIdx.x;
  const f32x4* src = (const f32x4*)(xc + (size_t)row * 2048);
  ((f32x4*)sx)[t] = src[t];
  ((f32x4*)sx)[t + 256] = src[t + 256];
  __syncthreads();
  for (int o = 0; o < 16; ++o) {
    const float* wr = (o < 8) ? (Wi + (size_t)o * 2048) : (Wf + (size_t)(o - 8) * 2048);
    float p = 0.f;
    for (int k2 = t; k2 < 2048; k2 += 256) p += sx[k2] * wr[k2];
    p = block_sum(p, red);
    if (t == 0) so[o] = p;
  }
  __syncthreads();
  if (t < 8) {
    const float it = so[t] + bi[t];
    const float ft = so[t + 8] + bfp[t];
    const float mp = m_tm1[row * 8 + t];
    const float m = fmaxf(ft + mp, it);
    m_out[row * 8 + t] = m;
    ig[row * 8 + t] = __expf(it - m);
    fg[row * 8 + t] = __expf(ft - m + mp);
  }
}

// ---------------------------------------------------------------- recurrence + GroupNorm + mix
__global__ __launch_bounds__(256)
void k_rec(const float* __restrict__ c_tm1, const float* __restrict__ n_tm1,
           const float* __restrict__ qb, const float* __restrict__ kb,
           const float* __restrict__ vb, const float* __restrict__ ot,
           const float* __restrict__ ig, const float* __restrict__ fg,
           const float* __restrict__ gn_g, const float* __restrict__ gn_b,
           const float* __restrict__ skipb, const float* __restrict__ sr,
           float* __restrict__ c_out, float* __restrict__ n_out,
           float* __restrict__ uf) {
  __shared__ float sk[128], sq[128], sv[128], snum[128];
  __shared__ float red[4];
  const int bh = blockIdx.x;
  const int b = bh >> 3, h = bh & 7;
  const int t = threadIdx.x;
  const size_t base = (size_t)b * 1024 + h * 128;
  if (t < 128) { sk[t] = kb[base + t]; sv[t] = vb[base + t]; }
  else         { sq[t - 128] = qb[base + t - 128]; }
  __syncthreads();
  const float fgv = fg[bh], igv = ig[bh];
  const float* C0 = c_tm1 + (size_t)bh * 16384;
  float* Ct = c_out + (size_t)bh * 16384;
  const int r0 = t >> 5, c4 = t & 31;
  const f32x4 k4 = ((const f32x4*)sk)[c4];
  const f32x4 q4 = ((const f32x4*)sq)[c4];
#pragma unroll 4
  for (int pass = 0; pass < 16; ++pass) {
    const int d = pass * 8 + r0;
    const f32x4 c0v = ((const f32x4*)C0)[d * 32 + c4];
    const float iv = igv * sv[d];
    f32x4 ct = fgv * c0v + iv * k4;
    ((f32x4*)Ct)[d * 32 + c4] = ct;
    float p = ct[0] * q4[0] + ct[1] * q4[1] + ct[2] * q4[2] + ct[3] * q4[3];
    p += __shfl_xor(p, 1, 64); p += __shfl_xor(p, 2, 64); p += __shfl_xor(p, 4, 64);
    p += __shfl_xor(p, 8, 64); p += __shfl_xor(p, 16, 64);
    if (c4 == 0) snum[d] = p;
  }
  __syncthreads();
  float denp = 0.f, ntd = 0.f;
  if (t < 128) {
    ntd = fgv * n_tm1[(size_t)bh * 128 + t] + igv * sk[t];
    n_out[(size_t)bh * 128 + t] = ntd;
    denp = ntd * sq[t];
  }
  const float den = fmaxf(block_sum(denp, red), 1.f);
  float hv = 0.f;
  if (t < 128) {
    const float o = 1.f / (1.f + __expf(-ot[base + t]));
    hv = o * snum[t] / den;
  }
  const float mu  = block_sum(hv, red) * (1.f / 128.f);
  const float var = block_sum(hv * hv, red) * (1.f / 128.f) - mu * mu;
  if (t < 128) {
    const int hid = h * 128 + t;
    const float hn = (hv - mu) * rsqrtf(var + LN_EPS) * gn_g[hid] + gn_b[hid];
    uf[base + t] = (hn + skipb[base + t]) * sr[base + t];
  }
}

// ---------------------------------------------------------------- multi-segment split-bf16 MFMA GEMM
// C[256, nseg*1024] = A[256,K](f32) @ seg.W[1024,K]^T (f32), per-seg epilogue.
// Precision: split x = hi(bf16) + lo(bf16); acc += Ah*Bh + Ah*Bl + Al*Bh  (~fp32).
// BM=64, BN=64, BK=64; 4 waves (2x2); XOR-swizzled LDS; reg-staged double buffer.
struct GemmSeg {
  const float* W; const float* bias; float* out;
  const float* add; int ldOut; int colOfs; int epi; float scale;
};
struct GemmArgs { GemmSeg seg[3]; };

__global__ __launch_bounds__(256)
void k_gemm(const float* __restrict__ A, int K, GemmArgs ga) {
  // per buffer (32KB): A_hi [0,8K) A_lo [8K,16K) W_hi [16K,24K) W_lo [24K,32K)
  __shared__ __align__(16) char lds[2][32768];
  const int tid = threadIdx.x;
  const int lane = tid & 63;
  const int wid = tid >> 6;
  const int wm = wid >> 1;
  const int wn = wid & 1;
  const int segId = blockIdx.x >> 4;
  const int n0 = (blockIdx.x & 15) * 64;
  const int m0 = blockIdx.y * 64;
  const GemmSeg sg = ga.seg[segId];

  const int lrow = tid >> 4;         // 0..15 (row within 16-row pass group)
  const int col4 = tid & 15;         // 16B (4-float) slot 0..15

  f32x4 acc[2][2] = {};

  const float* Abase = A + (size_t)m0 * K;
  const float* Wbase = sg.W + (size_t)n0 * K;
  const int NT = K >> 6;

  f32x4 va[4], vw[4], va2[4], vw2[4];
#pragma unroll
  for (int p = 0; p < 4; ++p) {
    const int r = p * 16 + lrow;
    va[p] = *(const f32x4*)(Abase + (size_t)r * K + col4 * 4);
    vw[p] = *(const f32x4*)(Wbase + (size_t)r * K + col4 * 4);
  }

  for (int kt = 0; kt < NT; ++kt) {
    // split + write current tile into LDS (swizzled in 16B slots: slot16 ^ (row&7))
    {
      char* lb = lds[kt & 1];
      const int byte = ((((col4 >> 1) ^ (lrow & 7)) << 4) | ((col4 & 1) << 3));
#pragma unroll
      for (int p = 0; p < 4; ++p) {
        const int r = p * 16 + lrow;           // r&7 == lrow&7
        bf16x4 ah, al, wh, wl;
#pragma unroll
        for (int i = 0; i < 4; ++i) {
          float v = va[p][i];
          __bf16 h = (__bf16)v;
          ah[i] = h; al[i] = (__bf16)(v - (float)h);
          v = vw[p][i];
          h = (__bf16)v;
          wh[i] = h; wl[i] = (__bf16)(v - (float)h);
        }
        *(bf16x4*)(lb + r * 128 + byte) = ah;
        *(bf16x4*)(lb + 8192 + r * 128 + byte) = al;
        *(bf16x4*)(lb + 16384 + r * 128 + byte) = wh;
        *(bf16x4*)(lb + 24576 + r * 128 + byte) = wl;
      }
    }
    // issue next tile's global loads (overlap with compute)
    if (kt + 1 < NT) {
      const int ko = (kt + 1) * 64;
#pragma unroll
      for (int p = 0; p < 4; ++p) {
        const int r = p * 16 + lrow;
        va2[p] = *(const f32x4*)(Abase + (size_t)r * K + ko + col4 * 4);
        vw2[p] = *(const f32x4*)(Wbase + (size_t)r * K + ko + col4 * 4);
      }
    }
    __syncthreads();
    {
      const char* lb = lds[kt & 1];
      const int rA = wm * 32 + (lane & 15);
      const int rB = wn * 32 + (lane & 15);
      const int kg = lane >> 4;
      const int swz = lane & 7;              // rA&7 == rB&7 == lane&7
#pragma unroll
      for (int kk = 0; kk < 2; ++kk) {
        const int so = ((kk * 4 + kg) ^ swz) << 4;
        const char* pa0 = lb + rA * 128 + so;
        const char* pa1 = lb + (rA + 16) * 128 + so;
        const char* pb0 = lb + 16384 + rB * 128 + so;
        const char* pb1 = lb + 16384 + (rB + 16) * 128 + so;
        const bf16x8 ah0 = *(const bf16x8*)(pa0);
        const bf16x8 al0 = *(const bf16x8*)(pa0 + 8192);
        const bf16x8 ah1 = *(const bf16x8*)(pa1);
        const bf16x8 al1 = *(const bf16x8*)(pa1 + 8192);
        const bf16x8 bh0 = *(const bf16x8*)(pb0);
        const bf16x8 bl0 = *(const bf16x8*)(pb0 + 8192);
        const bf16x8 bh1 = *(const bf16x8*)(pb1);
        const bf16x8 bl1 = *(const bf16x8*)(pb1 + 8192);
        acc[0][0] = __builtin_amdgcn_mfma_f32_16x16x32_bf16(ah0, bh0, acc[0][0], 0, 0, 0);
        acc[0][1] = __builtin_amdgcn_mfma_f32_16x16x32_bf16(ah0, bh1, acc[0][1], 0, 0, 0);
        acc[1][0] = __builtin_amdgcn_mfma_f32_16x16x32_bf16(ah1, bh0, acc[1][0], 0, 0, 0);
        acc[1][1] = __builtin_amdgcn_mfma_f32_16x16x32_bf16(ah1, bh1, acc[1][1], 0, 0, 0);
        acc[0][0] = __builtin_amdgcn_mfma_f32_16x16x32_bf16(ah0, bl0, acc[0][0], 0, 0, 0);
        acc[0][1] = __builtin_amdgcn_mfma_f32_16x16x32_bf16(ah0, bl1, acc[0][1], 0, 0, 0);
        acc[1][0] = __builtin_amdgcn_mfma_f32_16x16x32_bf16(ah1, bl0, acc[1][0], 0, 0, 0);
        acc[1][1] = __builtin_amdgcn_mfma_f32_16x16x32_bf16(ah1, bl1, acc[1][1], 0, 0, 0);
        acc[0][0] = __builtin_amdgcn_mfma_f32_16x16x32_bf16(al0, bh0, acc[0][0], 0, 0, 0);
        acc[0][1] = __builtin_amdgcn_mfma_f32_16x16x32_bf16(al0, bh1, acc[0][1], 0, 0, 0);
        acc[1][0] = __builtin_amdgcn_mfma_f32_16x16x32_bf16(al1, bh0, acc[1][0], 0, 0, 0);
        acc[1][1] = __builtin_amdgcn_mfma_f32_16x16x32_bf16(al1, bh1, acc[1][1], 0, 0, 0);
      }
    }
#pragma unroll
    for (int p = 0; p < 4; ++p) { va[p] = va2[p]; vw[p] = vw2[p]; }
    __syncthreads();
  }

  // epilogue: C/D layout col=lane&15, row=(lane>>4)*4+i
  const int rowb = m0 + wm * 32 + (lane >> 4) * 4;
  const int colb = n0 + wn * 32 + (lane & 15);
#pragma unroll
  for (int mf = 0; mf < 2; ++mf) {
#pragma unroll
    for (int nf = 0; nf < 2; ++nf) {
      const int col = colb + nf * 16;
      const float bv = sg.bias ? sg.bias[col] : 0.f;
#pragma unroll
      for (int i = 0; i < 4; ++i) {
        const int row = rowb + mf * 16 + i;
        float v = acc[mf][nf][i] + bv;
        if (sg.epi == 1)      v = v / (1.f + __expf(-v));       // silu
        else if (sg.epi == 3) v *= sg.scale;                    // scale
        else if (sg.epi == 4) v += sg.add[(size_t)row * 1024 + col];
        sg.out[(size_t)row * sg.ldOut + sg.colOfs + col] = v;
      }
    }
  }
}

// ---------------------------------------------------------------- host
extern "C" void kernel_launch(void* const* d_in, const int* in_sizes, int n_in,
                              void* d_out, int out_size, void* d_ws, size_t ws_size,
                              hipStream_t stream) {
  (void)in_sizes; (void)n_in; (void)out_size; (void)ws_size;
  const float* seq    = (const float*)d_in[0];
  const float* c_tm1  = (const float*)d_in[1];
  const float* n_tm1  = (const float*)d_in[2];
  const float* m_tm1  = (const float*)d_in[3];
  const float* ln_g   = (const float*)d_in[4];
  const float* ln_b   = (const float*)d_in[5];
  const float* gn_g   = (const float*)d_in[6];
  const float* gn_b   = (const float*)d_in[7];
  const float* W_upl  = (const float*)d_in[8];
  const float* b_upl  = (const float*)d_in[9];
  const float* W_upr  = (const float*)d_in[10];
  const float* b_upr  = (const float*)d_in[11];
  const float* W_down = (const float*)d_in[12];
  const float* b_down = (const float*)d_in[13];
  const float* W_last = (const float*)d_in[14];
  const float* b_last = (const float*)d_in[15];
  const float* conv_w = (const float*)d_in[16];
  const float* conv_b = (const float*)d_in[17];
  const float* W_skip = (const float*)d_in[18];
  const float* W_i    = (const float*)d_in[19];
  const float* b_i    = (const float*)d_in[20];
  const float* W_f    = (const float*)d_in[21];
  const float* b_f    = (const float*)d_in[22];
  const float* W_o    = (const float*)d_in[23];
  const float* b_o    = (const float*)d_in[24];
  const float* W_q    = (const float*)d_in[25];
  const float* b_q    = (const float*)d_in[26];
  const float* W_k    = (const float*)d_in[27];
  const float* b_k    = (const float*)d_in[28];
  const float* W_v    = (const float*)d_in[29];
  const float* b_v    = (const float*)d_in[30];

  float* out_final = (float*)d_out;
  float* out_c = out_final + (size_t)256 * 1024;
  float* out_n = out_c + (size_t)256 * 8 * 128 * 128;
  float* out_m = out_n + (size_t)256 * 8 * 128;

  char* ws = (char*)d_ws;
  size_t off = 0;
  auto alloc = [&](size_t bytes) -> void* {
    void* p = ws + off; off += (bytes + 255) & ~(size_t)255; return p;
  };
  float* x_n   = (float*)alloc((size_t)256 * 1024 * 4);
  float* x_t   = (float*)alloc((size_t)256 * 2048 * 4);
  float* sr    = (float*)alloc((size_t)256 * 1024 * 4);
  float* x_c   = (float*)alloc((size_t)256 * 2048 * 4);
  float* qb    = (float*)alloc((size_t)256 * 1024 * 4);
  float* kb    = (float*)alloc((size_t)256 * 1024 * 4);
  float* vb    = (float*)alloc((size_t)256 * 1024 * 4);
  float* otb   = (float*)alloc((size_t)256 * 1024 * 4);
  float* skipb = (float*)alloc((size_t)256 * 1024 * 4);
  float* igb   = (float*)alloc((size_t)2048 * 4);
  float* fgb   = (float*)alloc((size_t)2048 * 4);
  float* u_f   = (float*)alloc((size_t)256 * 1024 * 4);
  float* t_f   = (float*)alloc((size_t)256 * 1024 * 4);

  // 1. LayerNorm
  k_ln<<<256, 256, 0, stream>>>(seq, ln_g, ln_b, x_n);

  // 2. GEMM A: x_t (2 segs of W_upl) + silu(r_t), K=1024
  GemmArgs gA = {};
  gA.seg[0] = {W_upl, b_upl, x_t, nullptr, 2048, 0, 0, 0.f};
  gA.seg[1] = {W_upl + (size_t)1024 * 1024, b_upl + 1024, x_t, nullptr, 2048, 1024, 0, 0.f};
  gA.seg[2] = {W_upr, b_upr, sr, nullptr, 1024, 0, 1, 0.f};
  k_gemm<<<dim3(48, 4), 256, 0, stream>>>(x_n, 1024, gA);

  // 3. conv + silu
  k_conv<<<256, 256, 0, stream>>>(x_t, conv_w, conv_b, x_c);

  // 4. GEMM B: q, k(scaled), skip from x_c, K=2048
  GemmArgs gB = {};
  gB.seg[0] = {W_q, b_q, qb, nullptr, 1024, 0, 0, 0.f};
  gB.seg[1] = {W_k, b_k, kb, nullptr, 1024, 0, 3, 0.08838834764831845f};
  gB.seg[2] = {W_skip, nullptr, skipb, nullptr, 1024, 0, 0, 0.f};
  k_gemm<<<dim3(48, 4), 256, 0, stream>>>(x_c, 2048, gB);

  // 5. GEMM C: v, o(raw) from x_t, K=2048
  GemmArgs gC = {};
  gC.seg[0] = {W_v, b_v, vb, nullptr, 1024, 0, 0, 0.f};
  gC.seg[1] = {W_o, b_o, otb, nullptr, 1024, 0, 0, 0.f};
  k_gemm<<<dim3(32, 4), 256, 0, stream>>>(x_t, 2048, gC);

  // 6. i/f gates + stabilized gating (writes m_t to d_out)
  k_if<<<256, 256, 0, stream>>>(x_c, W_i, b_i, W_f, b_f, m_tm1, out_m, igb, fgb);

  // 7. recurrence: c_t, n_t (d_out), u = (GN(h)+skip)*silu(r)
  k_rec<<<2048, 256, 0, stream>>>(c_tm1, n_tm1, qb, kb, vb, otb, igb, fgb,
                                  gn_g, gn_b, skipb, sr, out_c, out_n, u_f);

  // 8. GEMM D: t = u @ W_down^T + b_down + x_n, K=1024
  GemmArgs gD = {};
  gD.seg[0] = {W_down, b_down, t_f, x_n, 1024, 0, 4, 0.f};
  k_gemm<<<dim3(16, 4), 256, 0, stream>>>(u_f, 1024, gD);

  // 9. GEMM E: final = t @ W_last^T + b_last -> d_out
  GemmArgs gE = {};
  gE.seg[0] = {W_last, b_last, out_final, nullptr, 1024, 0, 0, 0.f};
  k_gemm<<<dim3(16, 4), 256, 0, stream>>>(t_f, 1024, gE);
}

// Round 3
// 162.295 us; speedup vs baseline: 1.4118x; 1.4118x over previous
//
#include <hip/hip_runtime.h>
#include <cstdint>
#include <cstddef>

#define LN_EPS 1e-5f

typedef float  f32x4  __attribute__((ext_vector_type(4)));
typedef __bf16 bf16x8 __attribute__((ext_vector_type(8)));
typedef unsigned short u16x4 __attribute__((ext_vector_type(4)));

// ---------------------------------------------------------------- block reduce
__device__ __forceinline__ float block_sum(float v, volatile float* red) {
#pragma unroll
  for (int o = 32; o > 0; o >>= 1) v += __shfl_down(v, o, 64);
  const int lane = threadIdx.x & 63, w = threadIdx.x >> 6;
  __syncthreads();                 // protect red reuse across calls
  if (lane == 0) red[w] = v;
  __syncthreads();
  return red[0] + red[1] + red[2] + red[3];
}

// ---------------------------------------------------------------- LayerNorm
__global__ __launch_bounds__(256)
void k_ln(const float* __restrict__ seq, const float* __restrict__ g,
          const float* __restrict__ b, float* __restrict__ xn) {
  __shared__ float red[8];
  const int row = blockIdx.x, t = threadIdx.x;
  const f32x4 x = ((const f32x4*)(seq + (size_t)row * 1024))[t];
  float s  = x[0] + x[1] + x[2] + x[3];
  float s2 = x[0]*x[0] + x[1]*x[1] + x[2]*x[2] + x[3]*x[3];
#pragma unroll
  for (int o = 32; o > 0; o >>= 1) { s += __shfl_down(s, o, 64); s2 += __shfl_down(s2, o, 64); }
  const int lane = t & 63, w = t >> 6;
  if (lane == 0) { red[w] = s; red[4 + w] = s2; }
  __syncthreads();
  s  = red[0] + red[1] + red[2] + red[3];
  s2 = red[4] + red[5] + red[6] + red[7];
  const float mu  = s * (1.f / 1024.f);
  const float inv = rsqrtf(s2 * (1.f / 1024.f) - mu * mu + LN_EPS);
  const f32x4 gg = ((const f32x4*)g)[t];
  const f32x4 bb = ((const f32x4*)b)[t];
  f32x4 y;
#pragma unroll
  for (int i = 0; i < 4; ++i) y[i] = (x[i] - mu) * inv * gg[i] + bb[i];
  ((f32x4*)(xn + (size_t)row * 1024))[t] = y;
}

// ---------------------------------------------------------------- causal conv + silu
__global__ __launch_bounds__(256)
void k_conv(const float* __restrict__ xt, const float* __restrict__ cw,
            const float* __restrict__ cb, float* __restrict__ xc) {
  __shared__ float s[2048];
  const int row = blockIdx.x, t = threadIdx.x;
  const f32x4* src = (const f32x4*)(xt + (size_t)row * 2048);
  ((f32x4*)s)[t] = src[t];
  ((f32x4*)s)[t + 256] = src[t + 256];
  const float w0 = cw[0], w1 = cw[1], w2 = cw[2], w3 = cw[3], b = cb[0];
  __syncthreads();
  float out[8];
  const int c0 = t * 8;
#pragma unroll
  for (int j = 0; j < 8; ++j) {
    const int c = c0 + j;
    float a = b + w3 * s[c];
    if (c >= 1) a += w2 * s[c - 1];
    if (c >= 2) a += w1 * s[c - 2];
    if (c >= 3) a += w0 * s[c - 3];
    a = a / (1.f + __expf(-a));        // silu
    out[j] = a;
  }
  f32x4* dst = (f32x4*)(xc + (size_t)row * 2048 + c0);
  f32x4 v0 = {out[0], out[1], out[2], out[3]};
  f32x4 v1 = {out[4], out[5], out[6], out[7]};
  dst[0] = v0; dst[1] = v1;
}

// ---------------------------------------------------------------- i/f gates (wave-parallel)
__global__ __launch_bounds__(256)
void k_if(const float* __restrict__ xc, const float* __restrict__ Wi,
          const float* __restrict__ bi, const float* __restrict__ Wf,
          const float* __restrict__ bfp, const float* __restrict__ m_tm1,
          float* __restrict__ m_out, float* __restrict__ ig, float* __restrict__ fg) {
  __shared__ float sx[2048];
  __shared__ float so[16];
  const int row = blockIdx.x, t = threadIdx.x;
  const f32x4* src = (const f32x4*)(xc + (size_t)row * 2048);
  ((f32x4*)sx)[t] = src[t];
  ((f32x4*)sx)[t + 256] = src[t + 256];
  __syncthreads();
  const int w = t >> 6, lane = t & 63;
  // wave w computes outputs w*4 .. w*4+3 (o<8: i-gate rows, o>=8: f-gate rows)
  float p[4];
#pragma unroll
  for (int i = 0; i < 4; ++i) {
    const int o = w * 4 + i;
    const float* wr = (o < 8) ? (Wi + (size_t)o * 2048) : (Wf + (size_t)(o - 8) * 2048);
    float acc = 0.f;
#pragma unroll
    for (int j = 0; j < 8; ++j) {
      const f32x4 xv = ((const f32x4*)sx)[j * 64 + lane];
      const f32x4 wv = ((const f32x4*)wr)[j * 64 + lane];
      acc += xv[0]*wv[0] + xv[1]*wv[1] + xv[2]*wv[2] + xv[3]*wv[3];
    }
    p[i] = acc;
  }
#pragma unroll
  for (int i = 0; i < 4; ++i) {
#pragma unroll
    for (int o = 32; o > 0; o >>= 1) p[i] += __shfl_xor(p[i], o, 64);
  }
  if (lane == 0) {
#pragma unroll
    for (int i = 0; i < 4; ++i) so[w * 4 + i] = p[i];
  }
  __syncthreads();
  if (t < 8) {
    const float it = so[t] + bi[t];
    const float ft = so[t + 8] + bfp[t];
    const float mp = m_tm1[row * 8 + t];
    const float m = fmaxf(ft + mp, it);
    m_out[row * 8 + t] = m;
    ig[row * 8 + t] = __expf(it - m);
    fg[row * 8 + t] = __expf(ft - m + mp);
  }
}

// ---------------------------------------------------------------- recurrence + GroupNorm + mix
__global__ __launch_bounds__(256)
void k_rec(const float* __restrict__ c_tm1, const float* __restrict__ n_tm1,
           const float* __restrict__ qb, const float* __restrict__ kb,
           const float* __restrict__ vb, const float* __restrict__ ot,
           const float* __restrict__ ig, const float* __restrict__ fg,
           const float* __restrict__ gn_g, const float* __restrict__ gn_b,
           const float* __restrict__ skipb, const float* __restrict__ sr,
           float* __restrict__ c_out, float* __restrict__ n_out,
           float* __restrict__ uf) {
  __shared__ float sk[128], sq[128], sv[128], snum[128];
  __shared__ float red[4];
  const int bh = blockIdx.x;
  const int b = bh >> 3, h = bh & 7;
  const int t = threadIdx.x;
  const size_t base = (size_t)b * 1024 + h * 128;
  if (t < 128) { sk[t] = kb[base + t]; sv[t] = vb[base + t]; }
  else         { sq[t - 128] = qb[base + t - 128]; }
  __syncthreads();
  const float fgv = fg[bh], igv = ig[bh];
  const float* C0 = c_tm1 + (size_t)bh * 16384;
  float* Ct = c_out + (size_t)bh * 16384;
  const int r0 = t >> 5, c4 = t & 31;
  const f32x4 k4 = ((const f32x4*)sk)[c4];
  const f32x4 q4 = ((const f32x4*)sq)[c4];
  float pd[16];
  // pure streaming pass: no cross-lane ops inside
#pragma unroll
  for (int pass = 0; pass < 16; ++pass) {
    const int d = pass * 8 + r0;
    const f32x4 c0v = ((const f32x4*)C0)[d * 32 + c4];
    const float iv = igv * sv[d];
    f32x4 ct = fgv * c0v + iv * k4;
    __builtin_nontemporal_store(ct, ((f32x4*)Ct) + d * 32 + c4);
    pd[pass] = ct[0] * q4[0] + ct[1] * q4[1] + ct[2] * q4[2] + ct[3] * q4[3];
  }
  // 16 independent butterfly chains
#pragma unroll
  for (int pass = 0; pass < 16; ++pass) {
    float p = pd[pass];
    p += __shfl_xor(p, 1, 64); p += __shfl_xor(p, 2, 64); p += __shfl_xor(p, 4, 64);
    p += __shfl_xor(p, 8, 64); p += __shfl_xor(p, 16, 64);
    pd[pass] = p;
  }
  if (c4 == 0) {
#pragma unroll
    for (int pass = 0; pass < 16; ++pass) snum[pass * 8 + r0] = pd[pass];
  }
  float denp = 0.f, ntd = 0.f;
  if (t < 128) {
    ntd = fgv * n_tm1[(size_t)bh * 128 + t] + igv * sk[t];
    n_out[(size_t)bh * 128 + t] = ntd;
    denp = ntd * sq[t];
  }
  const float den = fmaxf(block_sum(denp, red), 1.f);   // block_sum syncs before/after
  float hv = 0.f;
  if (t < 128) {
    const float o = 1.f / (1.f + __expf(-ot[base + t]));
    hv = o * snum[t] / den;
  }
  const float mu  = block_sum(hv, red) * (1.f / 128.f);
  const float var = block_sum(hv * hv, red) * (1.f / 128.f) - mu * mu;
  if (t < 128) {
    const int hid = h * 128 + t;
    const float hn = (hv - mu) * rsqrtf(var + LN_EPS) * gn_g[hid] + gn_b[hid];
    uf[base + t] = (hv - mu) * 0.f + (hn + skipb[base + t]) * sr[base + t];
  }
}

// ---------------------------------------------------------------- multi-segment split-bf16 MFMA GEMM
// Per seg: C[256,1024] = A[256,K](f32) @ W[1024,K]^T (f32), per-seg epilogue.
// Precision: x = hi(bf16, trunc) + lo(bf16); acc += Ah*Bh + Ah*Bl + Al*Bh  (~fp32).
// BM=64, BN=64, BK=64; 4 waves (2x2); XOR-swizzled LDS; reg-staged double buffer.
struct GemmSeg {
  const float* A; const float* W; const float* bias; float* out;
  const float* add; int ldOut; int colOfs; int epi; float scale;
};
struct GemmArgs { GemmSeg seg[5]; };

__global__ __launch_bounds__(256)
void k_gemm(int K, GemmArgs ga) {
  // per buffer (32KB): A_hi [0,8K) A_lo [8K,16K) W_hi [16K,24K) W_lo [24K,32K)
  __shared__ __align__(16) char lds[2][32768];
  const int tid = threadIdx.x;
  const int lane = tid & 63;
  const int wid = tid >> 6;
  const int wm = wid >> 1;
  const int wn = wid & 1;
  const int segId = blockIdx.x >> 4;
  const int n0 = (blockIdx.x & 15) * 64;
  const int m0 = blockIdx.y * 64;
  const GemmSeg sg = ga.seg[segId];

  const int lrow = tid >> 4;         // 0..15 (row within 16-row pass group)
  const int col4 = tid & 15;         // 16B (4-float) slot 0..15

  f32x4 acc[2][2] = {};

  const float* Abase = sg.A + (size_t)m0 * K;
  const float* Wbase = sg.W + (size_t)n0 * K;
  const int NT = K >> 6;

  f32x4 va[4], vw[4], va2[4], vw2[4];
#pragma unroll
  for (int p = 0; p < 4; ++p) {
    const int r = p * 16 + lrow;
    va[p] = *(const f32x4*)(Abase + (size_t)r * K + col4 * 4);
    vw[p] = *(const f32x4*)(Wbase + (size_t)r * K + col4 * 4);
  }

  for (int kt = 0; kt < NT; ++kt) {
    // split (truncation) + write current tile into LDS (swizzled 16B slots)
    {
      char* lb = lds[kt & 1];
      const int byte = ((((col4 >> 1) ^ (lrow & 7)) << 4) | ((col4 & 1) << 3));
#pragma unroll
      for (int p = 0; p < 4; ++p) {
        const int r = p * 16 + lrow;           // r&7 == lrow&7
        u16x4 ah, al, wh, wl;
#pragma unroll
        for (int i = 0; i < 4; ++i) {
          const unsigned ab = __float_as_uint(va[p][i]);
          const float fh = __uint_as_float(ab & 0xFFFF0000u);
          ah[i] = (unsigned short)(ab >> 16);
          al[i] = (unsigned short)(__float_as_uint(va[p][i] - fh) >> 16);
          const unsigned wb2 = __float_as_uint(vw[p][i]);
          const float wfh = __uint_as_float(wb2 & 0xFFFF0000u);
          wh[i] = (unsigned short)(wb2 >> 16);
          wl[i] = (unsigned short)(__float_as_uint(vw[p][i] - wfh) >> 16);
        }
        *(u16x4*)(lb + r * 128 + byte) = ah;
        *(u16x4*)(lb + 8192 + r * 128 + byte) = al;
        *(u16x4*)(lb + 16384 + r * 128 + byte) = wh;
        *(u16x4*)(lb + 24576 + r * 128 + byte) = wl;
      }
    }
    // issue next tile's global loads (overlap with compute)
    if (kt + 1 < NT) {
      const int ko = (kt + 1) * 64;
#pragma unroll
      for (int p = 0; p < 4; ++p) {
        const int r = p * 16 + lrow;
        va2[p] = *(const f32x4*)(Abase + (size_t)r * K + ko + col4 * 4);
        vw2[p] = *(const f32x4*)(Wbase + (size_t)r * K + ko + col4 * 4);
      }
    }
    __syncthreads();
    {
      const char* lb = lds[kt & 1];
      const int rA = wm * 32 + (lane & 15);
      const int rB = wn * 32 + (lane & 15);
      const int kg = lane >> 4;
      const int swz = lane & 7;              // rA&7 == rB&7 == lane&7
#pragma unroll
      for (int kk = 0; kk < 2; ++kk) {
        const int so = ((kk * 4 + kg) ^ swz) << 4;
        const char* pa0 = lb + rA * 128 + so;
        const char* pa1 = lb + (rA + 16) * 128 + so;
        const char* pb0 = lb + 16384 + rB * 128 + so;
        const char* pb1 = lb + 16384 + (rB + 16) * 128 + so;
        const bf16x8 ah0 = *(const bf16x8*)(pa0);
        const bf16x8 al0 = *(const bf16x8*)(pa0 + 8192);
        const bf16x8 ah1 = *(const bf16x8*)(pa1);
        const bf16x8 al1 = *(const bf16x8*)(pa1 + 8192);
        const bf16x8 bh0 = *(const bf16x8*)(pb0);
        const bf16x8 bl0 = *(const bf16x8*)(pb0 + 8192);
        const bf16x8 bh1 = *(const bf16x8*)(pb1);
        const bf16x8 bl1 = *(const bf16x8*)(pb1 + 8192);
        acc[0][0] = __builtin_amdgcn_mfma_f32_16x16x32_bf16(ah0, bh0, acc[0][0], 0, 0, 0);
        acc[0][1] = __builtin_amdgcn_mfma_f32_16x16x32_bf16(ah0, bh1, acc[0][1], 0, 0, 0);
        acc[1][0] = __builtin_amdgcn_mfma_f32_16x16x32_bf16(ah1, bh0, acc[1][0], 0, 0, 0);
        acc[1][1] = __builtin_amdgcn_mfma_f32_16x16x32_bf16(ah1, bh1, acc[1][1], 0, 0, 0);
        acc[0][0] = __builtin_amdgcn_mfma_f32_16x16x32_bf16(ah0, bl0, acc[0][0], 0, 0, 0);
        acc[0][1] = __builtin_amdgcn_mfma_f32_16x16x32_bf16(ah0, bl1, acc[0][1], 0, 0, 0);
        acc[1][0] = __builtin_amdgcn_mfma_f32_16x16x32_bf16(ah1, bl0, acc[1][0], 0, 0, 0);
        acc[1][1] = __builtin_amdgcn_mfma_f32_16x16x32_bf16(ah1, bl1, acc[1][1], 0, 0, 0);
        acc[0][0] = __builtin_amdgcn_mfma_f32_16x16x32_bf16(al0, bh0, acc[0][0], 0, 0, 0);
        acc[0][1] = __builtin_amdgcn_mfma_f32_16x16x32_bf16(al0, bh1, acc[0][1], 0, 0, 0);
        acc[1][0] = __builtin_amdgcn_mfma_f32_16x16x32_bf16(al1, bh0, acc[1][0], 0, 0, 0);
        acc[1][1] = __builtin_amdgcn_mfma_f32_16x16x32_bf16(al1, bh1, acc[1][1], 0, 0, 0);
      }
    }
#pragma unroll
    for (int p = 0; p < 4; ++p) { va[p] = va2[p]; vw[p] = vw2[p]; }
    __syncthreads();
  }

  // epilogue: C/D layout col=lane&15, row=(lane>>4)*4+i
  const int rowb = m0 + wm * 32 + (lane >> 4) * 4;
  const int colb = n0 + wn * 32 + (lane & 15);
#pragma unroll
  for (int mf = 0; mf < 2; ++mf) {
#pragma unroll
    for (int nf = 0; nf < 2; ++nf) {
      const int col = colb + nf * 16;
      const float bv = sg.bias ? sg.bias[col] : 0.f;
#pragma unroll
      for (int i = 0; i < 4; ++i) {
        const int row = rowb + mf * 16 + i;
        float v = acc[mf][nf][i] + bv;
        if (sg.epi == 1)      v = v / (1.f + __expf(-v));       // silu
        else if (sg.epi == 3) v *= sg.scale;                    // scale
        else if (sg.epi == 4) v += sg.add[(size_t)row * 1024 + col];
        sg.out[(size_t)row * sg.ldOut + sg.colOfs + col] = v;
      }
    }
  }
}

// ---------------------------------------------------------------- host
extern "C" void kernel_launch(void* const* d_in, const int* in_sizes, int n_in,
                              void* d_out, int out_size, void* d_ws, size_t ws_size,
                              hipStream_t stream) {
  (void)in_sizes; (void)n_in; (void)out_size; (void)ws_size;
  const float* seq    = (const float*)d_in[0];
  const float* c_tm1  = (const float*)d_in[1];
  const float* n_tm1  = (const float*)d_in[2];
  const float* m_tm1  = (const float*)d_in[3];
  const float* ln_g   = (const float*)d_in[4];
  const float* ln_b   = (const float*)d_in[5];
  const float* gn_g   = (const float*)d_in[6];
  const float* gn_b   = (const float*)d_in[7];
  const float* W_upl  = (const float*)d_in[8];
  const float* b_upl  = (const float*)d_in[9];
  const float* W_upr  = (const float*)d_in[10];
  const float* b_upr  = (const float*)d_in[11];
  const float* W_down = (const float*)d_in[12];
  const float* b_down = (const float*)d_in[13];
  const float* W_last = (const float*)d_in[14];
  const float* b_last = (const float*)d_in[15];
  const float* conv_w = (const float*)d_in[16];
  const float* conv_b = (const float*)d_in[17];
  const float* W_skip = (const float*)d_in[18];
  const float* W_i    = (const float*)d_in[19];
  const float* b_i    = (const float*)d_in[20];
  const float* W_f    = (const float*)d_in[21];
  const float* b_f    = (const float*)d_in[22];
  const float* W_o    = (const float*)d_in[23];
  const float* b_o    = (const float*)d_in[24];
  const float* W_q    = (const float*)d_in[25];
  const float* b_q    = (const float*)d_in[26];
  const float* W_k    = (const float*)d_in[27];
  const float* b_k    = (const float*)d_in[28];
  const float* W_v    = (const float*)d_in[29];
  const float* b_v    = (const float*)d_in[30];

  float* out_final = (float*)d_out;
  float* out_c = out_final + (size_t)256 * 1024;
  float* out_n = out_c + (size_t)256 * 8 * 128 * 128;
  float* out_m = out_n + (size_t)256 * 8 * 128;

  char* ws = (char*)d_ws;
  size_t off = 0;
  auto alloc = [&](size_t bytes) -> void* {
    void* p = ws + off; off += (bytes + 255) & ~(size_t)255; return p;
  };
  float* x_n   = (float*)alloc((size_t)256 * 1024 * 4);
  float* x_t   = (float*)alloc((size_t)256 * 2048 * 4);
  float* sr    = (float*)alloc((size_t)256 * 1024 * 4);
  float* x_c   = (float*)alloc((size_t)256 * 2048 * 4);
  float* qb    = (float*)alloc((size_t)256 * 1024 * 4);
  float* kb    = (float*)alloc((size_t)256 * 1024 * 4);
  float* vb    = (float*)alloc((size_t)256 * 1024 * 4);
  float* otb   = (float*)alloc((size_t)256 * 1024 * 4);
  float* skipb = (float*)alloc((size_t)256 * 1024 * 4);
  float* igb   = (float*)alloc((size_t)2048 * 4);
  float* fgb   = (float*)alloc((size_t)2048 * 4);
  float* u_f   = (float*)alloc((size_t)256 * 1024 * 4);
  float* t_f   = (float*)alloc((size_t)256 * 1024 * 4);

  // 1. LayerNorm
  k_ln<<<256, 256, 0, stream>>>(seq, ln_g, ln_b, x_n);

  // 2. GEMM A: x_t (2 segs of W_upl) + silu(r_t), K=1024
  GemmArgs gA = {};
  gA.seg[0] = {x_n, W_upl, b_upl, x_t, nullptr, 2048, 0, 0, 0.f};
  gA.seg[1] = {x_n, W_upl + (size_t)1024 * 1024, b_upl + 1024, x_t, nullptr, 2048, 1024, 0, 0.f};
  gA.seg[2] = {x_n, W_upr, b_upr, sr, nullptr, 1024, 0, 1, 0.f};
  k_gemm<<<dim3(48, 4), 256, 0, stream>>>(1024, gA);

  // 3. conv + silu
  k_conv<<<256, 256, 0, stream>>>(x_t, conv_w, conv_b, x_c);

  // 4. i/f gates + stabilized gating (writes m_t to d_out)
  k_if<<<256, 256, 0, stream>>>(x_c, W_i, b_i, W_f, b_f, m_tm1, out_m, igb, fgb);

  // 5. GEMM B+C merged: q, k(scaled), skip from x_c; v, o from x_t; K=2048
  GemmArgs gBC = {};
  gBC.seg[0] = {x_c, W_q, b_q, qb, nullptr, 1024, 0, 0, 0.f};
  gBC.seg[1] = {x_c, W_k, b_k, kb, nullptr, 1024, 0, 3, 0.08838834764831845f};
  gBC.seg[2] = {x_c, W_skip, nullptr, skipb, nullptr, 1024, 0, 0, 0.f};
  gBC.seg[3] = {x_t, W_v, b_v, vb, nullptr, 1024, 0, 0, 0.f};
  gBC.seg[4] = {x_t, W_o, b_o, otb, nullptr, 1024, 0, 0, 0.f};
  k_gemm<<<dim3(80, 4), 256, 0, stream>>>(2048, gBC);

  // 6. recurrence: c_t, n_t (d_out), u = (GN(h)+skip)*silu(r)
  k_rec<<<2048, 256, 0, stream>>>(c_tm1, n_tm1, qb, kb, vb, otb, igb, fgb,
                                  gn_g, gn_b, skipb, sr, out_c, out_n, u_f);

  // 7. GEMM D: t = u @ W_down^T + b_down + x_n, K=1024
  GemmArgs gD = {};
  gD.seg[0] = {u_f, W_down, b_down, t_f, x_n, 1024, 0, 4, 0.f};
  k_gemm<<<dim3(16, 4), 256, 0, stream>>>(1024, gD);

  // 8. GEMM E: final = t @ W_last^T + b_last -> d_out
  GemmArgs gE = {};
  gE.seg[0] = {t_f, W_last, b_last, out_final, nullptr, 1024, 0, 0, 0.f};
  k_gemm<<<dim3(16, 4), 256, 0, stream>>>(1024, gE);
}

// Round 4
// 161.999 us; speedup vs baseline: 1.4144x; 1.0018x over previous
//
#include <hip/hip_runtime.h>
#include <cstdint>
#include <cstddef>

#define LN_EPS 1e-5f

typedef float  f32x4  __attribute__((ext_vector_type(4)));
typedef __bf16 bf16x8 __attribute__((ext_vector_type(8)));
typedef unsigned short u16x4 __attribute__((ext_vector_type(4)));

// ---------------------------------------------------------------- block reduce
__device__ __forceinline__ float block_sum(float v, volatile float* red) {
#pragma unroll
  for (int o = 32; o > 0; o >>= 1) v += __shfl_down(v, o, 64);
  const int lane = threadIdx.x & 63, w = threadIdx.x >> 6;
  __syncthreads();                 // protect red reuse across calls
  if (lane == 0) red[w] = v;
  __syncthreads();
  return red[0] + red[1] + red[2] + red[3];
}

// ---------------------------------------------------------------- LayerNorm
__global__ __launch_bounds__(256)
void k_ln(const float* __restrict__ seq, const float* __restrict__ g,
          const float* __restrict__ b, float* __restrict__ xn) {
  __shared__ float red[8];
  const int row = blockIdx.x, t = threadIdx.x;
  const f32x4 x = ((const f32x4*)(seq + (size_t)row * 1024))[t];
  float s  = x[0] + x[1] + x[2] + x[3];
  float s2 = x[0]*x[0] + x[1]*x[1] + x[2]*x[2] + x[3]*x[3];
#pragma unroll
  for (int o = 32; o > 0; o >>= 1) { s += __shfl_down(s, o, 64); s2 += __shfl_down(s2, o, 64); }
  const int lane = t & 63, w = t >> 6;
  if (lane == 0) { red[w] = s; red[4 + w] = s2; }
  __syncthreads();
  s  = red[0] + red[1] + red[2] + red[3];
  s2 = red[4] + red[5] + red[6] + red[7];
  const float mu  = s * (1.f / 1024.f);
  const float inv = rsqrtf(s2 * (1.f / 1024.f) - mu * mu + LN_EPS);
  const f32x4 gg = ((const f32x4*)g)[t];
  const f32x4 bb = ((const f32x4*)b)[t];
  f32x4 y;
#pragma unroll
  for (int i = 0; i < 4; ++i) y[i] = (x[i] - mu) * inv * gg[i] + bb[i];
  ((f32x4*)(xn + (size_t)row * 1024))[t] = y;
}

// ---------------------------------------------------------------- causal conv + silu
__global__ __launch_bounds__(256)
void k_conv(const float* __restrict__ xt, const float* __restrict__ cw,
            const float* __restrict__ cb, float* __restrict__ xc) {
  __shared__ float s[2048];
  const int row = blockIdx.x, t = threadIdx.x;
  const f32x4* src = (const f32x4*)(xt + (size_t)row * 2048);
  ((f32x4*)s)[t] = src[t];
  ((f32x4*)s)[t + 256] = src[t + 256];
  const float w0 = cw[0], w1 = cw[1], w2 = cw[2], w3 = cw[3], b = cb[0];
  __syncthreads();
  float out[8];
  const int c0 = t * 8;
#pragma unroll
  for (int j = 0; j < 8; ++j) {
    const int c = c0 + j;
    float a = b + w3 * s[c];
    if (c >= 1) a += w2 * s[c - 1];
    if (c >= 2) a += w1 * s[c - 2];
    if (c >= 3) a += w0 * s[c - 3];
    a = a / (1.f + __expf(-a));        // silu
    out[j] = a;
  }
  f32x4* dst = (f32x4*)(xc + (size_t)row * 2048 + c0);
  f32x4 v0 = {out[0], out[1], out[2], out[3]};
  f32x4 v1 = {out[4], out[5], out[6], out[7]};
  dst[0] = v0; dst[1] = v1;
}

// ---------------------------------------------------------------- i/f gates (wave-parallel)
__global__ __launch_bounds__(256)
void k_if(const float* __restrict__ xc, const float* __restrict__ Wi,
          const float* __restrict__ bi, const float* __restrict__ Wf,
          const float* __restrict__ bfp, const float* __restrict__ m_tm1,
          float* __restrict__ m_out, float* __restrict__ ig, float* __restrict__ fg) {
  __shared__ float sx[2048];
  __shared__ float so[16];
  const int row = blockIdx.x, t = threadIdx.x;
  const f32x4* src = (const f32x4*)(xc + (size_t)row * 2048);
  ((f32x4*)sx)[t] = src[t];
  ((f32x4*)sx)[t + 256] = src[t + 256];
  __syncthreads();
  const int w = t >> 6, lane = t & 63;
  float p[4];
#pragma unroll
  for (int i = 0; i < 4; ++i) {
    const int o = w * 4 + i;
    const float* wr = (o < 8) ? (Wi + (size_t)o * 2048) : (Wf + (size_t)(o - 8) * 2048);
    float acc = 0.f;
#pragma unroll
    for (int j = 0; j < 8; ++j) {
      const f32x4 xv = ((const f32x4*)sx)[j * 64 + lane];
      const f32x4 wv = ((const f32x4*)wr)[j * 64 + lane];
      acc += xv[0]*wv[0] + xv[1]*wv[1] + xv[2]*wv[2] + xv[3]*wv[3];
    }
    p[i] = acc;
  }
#pragma unroll
  for (int i = 0; i < 4; ++i) {
#pragma unroll
    for (int o = 32; o > 0; o >>= 1) p[i] += __shfl_xor(p[i], o, 64);
  }
  if (lane == 0) {
#pragma unroll
    for (int i = 0; i < 4; ++i) so[w * 4 + i] = p[i];
  }
  __syncthreads();
  if (t < 8) {
    const float it = so[t] + bi[t];
    const float ft = so[t + 8] + bfp[t];
    const float mp = m_tm1[row * 8 + t];
    const float m = fmaxf(ft + mp, it);
    m_out[row * 8 + t] = m;
    ig[row * 8 + t] = __expf(it - m);
    fg[row * 8 + t] = __expf(ft - m + mp);
  }
}

// ---------------------------------------------------------------- recurrence + GroupNorm + mix
// 8-deep register-staged streaming pipeline; __launch_bounds__(256,4) -> <=128 VGPR
// so all 8 staged f32x4 loads stay in flight (R3 ran at VGPR=32 => serialized loads).
__global__ __launch_bounds__(256, 4)
void k_rec(const float* __restrict__ c_tm1, const float* __restrict__ n_tm1,
           const float* __restrict__ qb, const float* __restrict__ kb,
           const float* __restrict__ vb, const float* __restrict__ ot,
           const float* __restrict__ ig, const float* __restrict__ fg,
           const float* __restrict__ gn_g, const float* __restrict__ gn_b,
           const float* __restrict__ skipb, const float* __restrict__ sr,
           float* __restrict__ c_out, float* __restrict__ n_out,
           float* __restrict__ uf) {
  __shared__ float sk[128], sq[128], sv[128], snum[128];
  __shared__ float red[4];
  const int bh = blockIdx.x;
  const int b = bh >> 3, h = bh & 7;
  const int t = threadIdx.x;
  const size_t base = (size_t)b * 1024 + h * 128;
  if (t < 128) { sk[t] = kb[base + t]; sv[t] = vb[base + t]; }
  else         { sq[t - 128] = qb[base + t - 128]; }
  __syncthreads();
  const float fgv = fg[bh], igv = ig[bh];
  const f32x4* C0 = (const f32x4*)(c_tm1 + (size_t)bh * 16384);
  f32x4* Ct = (f32x4*)(c_out + (size_t)bh * 16384);
  const int r0 = t >> 5, c4 = t & 31;
  const f32x4 k4 = ((const f32x4*)sk)[c4];
  const f32x4 q4 = ((const f32x4*)sq)[c4];
  float pd[16];
  f32x4 st[8];
  // prologue: stage first 8 rows' loads (independent, all in flight)
#pragma unroll
  for (int p = 0; p < 8; ++p) st[p] = C0[(p * 8 + r0) * 32 + c4];
#pragma unroll
  for (int g = 0; g < 2; ++g) {
#pragma unroll
    for (int p = 0; p < 8; ++p) {
      const int pass = g * 8 + p;
      const int d = pass * 8 + r0;
      const f32x4 c0v = st[p];
      if (g == 0) st[p] = C0[((8 + p) * 8 + r0) * 32 + c4];   // issue next-group load
      const float iv = igv * sv[d];
      f32x4 ct = fgv * c0v + iv * k4;
      __builtin_nontemporal_store(ct, Ct + d * 32 + c4);
      pd[pass] = ct[0] * q4[0] + ct[1] * q4[1] + ct[2] * q4[2] + ct[3] * q4[3];
    }
  }
  // 16 independent butterfly chains
#pragma unroll
  for (int pass = 0; pass < 16; ++pass) {
    float p = pd[pass];
    p += __shfl_xor(p, 1, 64); p += __shfl_xor(p, 2, 64); p += __shfl_xor(p, 4, 64);
    p += __shfl_xor(p, 8, 64); p += __shfl_xor(p, 16, 64);
    pd[pass] = p;
  }
  if (c4 == 0) {
#pragma unroll
    for (int pass = 0; pass < 16; ++pass) snum[pass * 8 + r0] = pd[pass];
  }
  float denp = 0.f, ntd = 0.f;
  if (t < 128) {
    ntd = fgv * n_tm1[(size_t)bh * 128 + t] + igv * sk[t];
    n_out[(size_t)bh * 128 + t] = ntd;
    denp = ntd * sq[t];
  }
  const float den = fmaxf(block_sum(denp, red), 1.f);   // block_sum syncs before/after
  float hv = 0.f;
  if (t < 128) {
    const float o = 1.f / (1.f + __expf(-ot[base + t]));
    hv = o * snum[t] / den;
  }
  const float mu  = block_sum(hv, red) * (1.f / 128.f);
  const float var = block_sum(hv * hv, red) * (1.f / 128.f) - mu * mu;
  if (t < 128) {
    const int hid = h * 128 + t;
    const float hn = (hv - mu) * rsqrtf(var + LN_EPS) * gn_g[hid] + gn_b[hid];
    uf[base + t] = (hn + skipb[base + t]) * sr[base + t];
  }
}

// ---------------------------------------------------------------- multi-segment split-bf16 MFMA GEMM
// Per seg: C[256,1024] = A[256,K](f32) @ W[1024,K]^T (f32), per-seg epilogue.
// Precision: x = hi(bf16, trunc) + lo(bf16); acc += Ah*Bh + Ah*Bl + Al*Bh  (~fp32).
// BM=64, BN=64, BK=64; 4 waves (2x2); XOR-swizzled LDS; reg-staged double buffer.
struct GemmSeg {
  const float* A; const float* W; const float* bias; float* out;
  const float* add; int ldOut; int colOfs; int epi; float scale;
};
struct GemmArgs { GemmSeg seg[5]; };

__global__ __launch_bounds__(256)
void k_gemm(int K, GemmArgs ga) {
  // per buffer (32KB): A_hi [0,8K) A_lo [8K,16K) W_hi [16K,24K) W_lo [24K,32K)
  __shared__ __align__(16) char lds[2][32768];
  const int tid = threadIdx.x;
  const int lane = tid & 63;
  const int wid = tid >> 6;
  const int wm = wid >> 1;
  const int wn = wid & 1;
  const int segId = blockIdx.x >> 4;
  const int n0 = (blockIdx.x & 15) * 64;
  const int m0 = blockIdx.y * 64;
  const GemmSeg sg = ga.seg[segId];

  const int lrow = tid >> 4;         // 0..15 (row within 16-row pass group)
  const int col4 = tid & 15;         // 16B (4-float) slot 0..15

  f32x4 acc[2][2] = {};

  const float* Abase = sg.A + (size_t)m0 * K;
  const float* Wbase = sg.W + (size_t)n0 * K;
  const int NT = K >> 6;

  f32x4 va[4], vw[4], va2[4], vw2[4];
#pragma unroll
  for (int p = 0; p < 4; ++p) {
    const int r = p * 16 + lrow;
    va[p] = *(const f32x4*)(Abase + (size_t)r * K + col4 * 4);
    vw[p] = *(const f32x4*)(Wbase + (size_t)r * K + col4 * 4);
  }

  for (int kt = 0; kt < NT; ++kt) {
    // split (truncation) + write current tile into LDS (swizzled 16B slots)
    {
      char* lb = lds[kt & 1];
      const int byte = ((((col4 >> 1) ^ (lrow & 7)) << 4) | ((col4 & 1) << 3));
#pragma unroll
      for (int p = 0; p < 4; ++p) {
        const int r = p * 16 + lrow;           // r&7 == lrow&7
        u16x4 ah, al, wh, wl;
#pragma unroll
        for (int i = 0; i < 4; ++i) {
          const unsigned ab = __float_as_uint(va[p][i]);
          const float fh = __uint_as_float(ab & 0xFFFF0000u);
          ah[i] = (unsigned short)(ab >> 16);
          al[i] = (unsigned short)(__float_as_uint(va[p][i] - fh) >> 16);
          const unsigned wb2 = __float_as_uint(vw[p][i]);
          const float wfh = __uint_as_float(wb2 & 0xFFFF0000u);
          wh[i] = (unsigned short)(wb2 >> 16);
          wl[i] = (unsigned short)(__float_as_uint(vw[p][i] - wfh) >> 16);
        }
        *(u16x4*)(lb + r * 128 + byte) = ah;
        *(u16x4*)(lb + 8192 + r * 128 + byte) = al;
        *(u16x4*)(lb + 16384 + r * 128 + byte) = wh;
        *(u16x4*)(lb + 24576 + r * 128 + byte) = wl;
      }
    }
    // issue next tile's global loads (overlap with compute)
    if (kt + 1 < NT) {
      const int ko = (kt + 1) * 64;
#pragma unroll
      for (int p = 0; p < 4; ++p) {
        const int r = p * 16 + lrow;
        va2[p] = *(const f32x4*)(Abase + (size_t)r * K + ko + col4 * 4);
        vw2[p] = *(const f32x4*)(Wbase + (size_t)r * K + ko + col4 * 4);
      }
    }
    __syncthreads();
    {
      const char* lb = lds[kt & 1];
      const int rA = wm * 32 + (lane & 15);
      const int rB = wn * 32 + (lane & 15);
      const int kg = lane >> 4;
      const int swz = lane & 7;              // rA&7 == rB&7 == lane&7
#pragma unroll
      for (int kk = 0; kk < 2; ++kk) {
        const int so = ((kk * 4 + kg) ^ swz) << 4;
        const char* pa0 = lb + rA * 128 + so;
        const char* pa1 = lb + (rA + 16) * 128 + so;
        const char* pb0 = lb + 16384 + rB * 128 + so;
        const char* pb1 = lb + 16384 + (rB + 16) * 128 + so;
        const bf16x8 ah0 = *(const bf16x8*)(pa0);
        const bf16x8 al0 = *(const bf16x8*)(pa0 + 8192);
        const bf16x8 ah1 = *(const bf16x8*)(pa1);
        const bf16x8 al1 = *(const bf16x8*)(pa1 + 8192);
        const bf16x8 bh0 = *(const bf16x8*)(pb0);
        const bf16x8 bl0 = *(const bf16x8*)(pb0 + 8192);
        const bf16x8 bh1 = *(const bf16x8*)(pb1);
        const bf16x8 bl1 = *(const bf16x8*)(pb1 + 8192);
        acc[0][0] = __builtin_amdgcn_mfma_f32_16x16x32_bf16(ah0, bh0, acc[0][0], 0, 0, 0);
        acc[0][1] = __builtin_amdgcn_mfma_f32_16x16x32_bf16(ah0, bh1, acc[0][1], 0, 0, 0);
        acc[1][0] = __builtin_amdgcn_mfma_f32_16x16x32_bf16(ah1, bh0, acc[1][0], 0, 0, 0);
        acc[1][1] = __builtin_amdgcn_mfma_f32_16x16x32_bf16(ah1, bh1, acc[1][1], 0, 0, 0);
        acc[0][0] = __builtin_amdgcn_mfma_f32_16x16x32_bf16(ah0, bl0, acc[0][0], 0, 0, 0);
        acc[0][1] = __builtin_amdgcn_mfma_f32_16x16x32_bf16(ah0, bl1, acc[0][1], 0, 0, 0);
        acc[1][0] = __builtin_amdgcn_mfma_f32_16x16x32_bf16(ah1, bl0, acc[1][0], 0, 0, 0);
        acc[1][1] = __builtin_amdgcn_mfma_f32_16x16x32_bf16(ah1, bl1, acc[1][1], 0, 0, 0);
        acc[0][0] = __builtin_amdgcn_mfma_f32_16x16x32_bf16(al0, bh0, acc[0][0], 0, 0, 0);
        acc[0][1] = __builtin_amdgcn_mfma_f32_16x16x32_bf16(al0, bh1, acc[0][1], 0, 0, 0);
        acc[1][0] = __builtin_amdgcn_mfma_f32_16x16x32_bf16(al1, bh0, acc[1][0], 0, 0, 0);
        acc[1][1] = __builtin_amdgcn_mfma_f32_16x16x32_bf16(al1, bh1, acc[1][1], 0, 0, 0);
      }
    }
#pragma unroll
    for (int p = 0; p < 4; ++p) { va[p] = va2[p]; vw[p] = vw2[p]; }
    __syncthreads();
  }

  // epilogue: C/D layout col=lane&15, row=(lane>>4)*4+i
  const int rowb = m0 + wm * 32 + (lane >> 4) * 4;
  const int colb = n0 + wn * 32 + (lane & 15);
#pragma unroll
  for (int mf = 0; mf < 2; ++mf) {
#pragma unroll
    for (int nf = 0; nf < 2; ++nf) {
      const int col = colb + nf * 16;
      const float bv = sg.bias ? sg.bias[col] : 0.f;
#pragma unroll
      for (int i = 0; i < 4; ++i) {
        const int row = rowb + mf * 16 + i;
        float v = acc[mf][nf][i] + bv;
        if (sg.epi == 1)      v = v / (1.f + __expf(-v));       // silu
        else if (sg.epi == 3) v *= sg.scale;                    // scale
        else if (sg.epi == 4) v += sg.add[(size_t)row * 1024 + col];
        sg.out[(size_t)row * sg.ldOut + sg.colOfs + col] = v;
      }
    }
  }
}

// ---------------------------------------------------------------- host
extern "C" void kernel_launch(void* const* d_in, const int* in_sizes, int n_in,
                              void* d_out, int out_size, void* d_ws, size_t ws_size,
                              hipStream_t stream) {
  (void)in_sizes; (void)n_in; (void)out_size; (void)ws_size;
  const float* seq    = (const float*)d_in[0];
  const float* c_tm1  = (const float*)d_in[1];
  const float* n_tm1  = (const float*)d_in[2];
  const float* m_tm1  = (const float*)d_in[3];
  const float* ln_g   = (const float*)d_in[4];
  const float* ln_b   = (const float*)d_in[5];
  const float* gn_g   = (const float*)d_in[6];
  const float* gn_b   = (const float*)d_in[7];
  const float* W_upl  = (const float*)d_in[8];
  const float* b_upl  = (const float*)d_in[9];
  const float* W_upr  = (const float*)d_in[10];
  const float* b_upr  = (const float*)d_in[11];
  const float* W_down = (const float*)d_in[12];
  const float* b_down = (const float*)d_in[13];
  const float* W_last = (const float*)d_in[14];
  const float* b_last = (const float*)d_in[15];
  const float* conv_w = (const float*)d_in[16];
  const float* conv_b = (const float*)d_in[17];
  const float* W_skip = (const float*)d_in[18];
  const float* W_i    = (const float*)d_in[19];
  const float* b_i    = (const float*)d_in[20];
  const float* W_f    = (const float*)d_in[21];
  const float* b_f    = (const float*)d_in[22];
  const float* W_o    = (const float*)d_in[23];
  const float* b_o    = (const float*)d_in[24];
  const float* W_q    = (const float*)d_in[25];
  const float* b_q    = (const float*)d_in[26];
  const float* W_k    = (const float*)d_in[27];
  const float* b_k    = (const float*)d_in[28];
  const float* W_v    = (const float*)d_in[29];
  const float* b_v    = (const float*)d_in[30];

  float* out_final = (float*)d_out;
  float* out_c = out_final + (size_t)256 * 1024;
  float* out_n = out_c + (size_t)256 * 8 * 128 * 128;
  float* out_m = out_n + (size_t)256 * 8 * 128;

  char* ws = (char*)d_ws;
  size_t off = 0;
  auto alloc = [&](size_t bytes) -> void* {
    void* p = ws + off; off += (bytes + 255) & ~(size_t)255; return p;
  };
  float* x_n   = (float*)alloc((size_t)256 * 1024 * 4);
  float* x_t   = (float*)alloc((size_t)256 * 2048 * 4);
  float* sr    = (float*)alloc((size_t)256 * 1024 * 4);
  float* x_c   = (float*)alloc((size_t)256 * 2048 * 4);
  float* qb    = (float*)alloc((size_t)256 * 1024 * 4);
  float* kb    = (float*)alloc((size_t)256 * 1024 * 4);
  float* vb    = (float*)alloc((size_t)256 * 1024 * 4);
  float* otb   = (float*)alloc((size_t)256 * 1024 * 4);
  float* skipb = (float*)alloc((size_t)256 * 1024 * 4);
  float* igb   = (float*)alloc((size_t)2048 * 4);
  float* fgb   = (float*)alloc((size_t)2048 * 4);
  float* u_f   = (float*)alloc((size_t)256 * 1024 * 4);
  float* t_f   = (float*)alloc((size_t)256 * 1024 * 4);

  // 1. LayerNorm
  k_ln<<<256, 256, 0, stream>>>(seq, ln_g, ln_b, x_n);

  // 2. GEMM A: x_t (2 segs of W_upl) + silu(r_t), K=1024
  GemmArgs gA = {};
  gA.seg[0] = {x_n, W_upl, b_upl, x_t, nullptr, 2048, 0, 0, 0.f};
  gA.seg[1] = {x_n, W_upl + (size_t)1024 * 1024, b_upl + 1024, x_t, nullptr, 2048, 1024, 0, 0.f};
  gA.seg[2] = {x_n, W_upr, b_upr, sr, nullptr, 1024, 0, 1, 0.f};
  k_gemm<<<dim3(48, 4), 256, 0, stream>>>(1024, gA);

  // 3. conv + silu
  k_conv<<<256, 256, 0, stream>>>(x_t, conv_w, conv_b, x_c);

  // 4. i/f gates + stabilized gating (writes m_t to d_out)
  k_if<<<256, 256, 0, stream>>>(x_c, W_i, b_i, W_f, b_f, m_tm1, out_m, igb, fgb);

  // 5. GEMM B+C merged: q, k(scaled), skip from x_c; v, o from x_t; K=2048
  GemmArgs gBC = {};
  gBC.seg[0] = {x_c, W_q, b_q, qb, nullptr, 1024, 0, 0, 0.f};
  gBC.seg[1] = {x_c, W_k, b_k, kb, nullptr, 1024, 0, 3, 0.08838834764831845f};
  gBC.seg[2] = {x_c, W_skip, nullptr, skipb, nullptr, 1024, 0, 0, 0.f};
  gBC.seg[3] = {x_t, W_v, b_v, vb, nullptr, 1024, 0, 0, 0.f};
  gBC.seg[4] = {x_t, W_o, b_o, otb, nullptr, 1024, 0, 0, 0.f};
  k_gemm<<<dim3(80, 4), 256, 0, stream>>>(2048, gBC);

  // 6. recurrence: c_t, n_t (d_out), u = (GN(h)+skip)*silu(r)
  k_rec<<<2048, 256, 0, stream>>>(c_tm1, n_tm1, qb, kb, vb, otb, igb, fgb,
                                  gn_g, gn_b, skipb, sr, out_c, out_n, u_f);

  // 7. GEMM D: t = u @ W_down^T + b_down + x_n, K=1024
  GemmArgs gD = {};
  gD.seg[0] = {u_f, W_down, b_down, t_f, x_n, 1024, 0, 4, 0.f};
  k_gemm<<<dim3(16, 4), 256, 0, stream>>>(1024, gD);

  // 8. GEMM E: final = t @ W_last^T + b_last -> d_out
  GemmArgs gE = {};
  gE.seg[0] = {t_f, W_last, b_last, out_final, nullptr, 1024, 0, 0, 0.f};
  k_gemm<<<dim3(16, 4), 256, 0, stream>>>(1024, gE);
}